// Round 2
// baseline (612.753 us; speedup 1.0000x reference)
//
#include <hip/hip_runtime.h>
#include <hip/hip_bf16.h>

typedef unsigned short ushort_t;
typedef __attribute__((ext_vector_type(8))) short bf16x8;
typedef __attribute__((ext_vector_type(4))) float f32x4;
typedef __attribute__((ext_vector_type(4))) int i32x4;
typedef __attribute__((ext_vector_type(2))) int i32x2;

#define MFMA16(A, B, C) __builtin_amdgcn_mfma_f32_16x16x32_bf16(A, B, C, 0, 0, 0)

#if defined(__has_builtin)
#if __has_builtin(__builtin_amdgcn_exp2f)
#define EXP2(x) __builtin_amdgcn_exp2f(x)
#else
#define EXP2(x) exp2f(x)
#endif
#else
#define EXP2(x) exp2f(x)
#endif

static constexpr int BATCH = 4;
static constexpr int DEP = 2048;
static constexpr int NH = 8;
static constexpr int CW = 128;   // per-head q/k/v width
static constexpr int HBn = 32;   // NH*BATCH
// log2(e)/sqrt(2048): folded into Q at projection so softmax logits use raw exp2
static constexpr float QSCALE = (float)(1.4426950408889634 / 45.254833995939045);

static __device__ __forceinline__ ushort_t f2bf(float f) {
  __hip_bfloat16 h = __float2bfloat16(f);
  return __builtin_bit_cast(ushort_t, h);
}
static __device__ __forceinline__ float bf2f(ushort_t u) {
  unsigned int v = ((unsigned int)u) << 16;
  return __builtin_bit_cast(float, v);
}

// ---------------------------------------------------------------------------
// Kernel 1: pointwise QKV projection (Q pre-scaled by QSCALE).
//   q_ws/k_ws: bf16 [32 hb][2048 d][128 c];  vt_ws: bf16 [32 hb][128 c][2048 d]
// ---------------------------------------------------------------------------
__global__ __launch_bounds__(256) void proj_kernel(
    const float* __restrict__ feat,
    const float* __restrict__ Wq, const float* __restrict__ bq,
    const float* __restrict__ Wk, const float* __restrict__ bk,
    const float* __restrict__ Wv, const float* __restrict__ bv,
    ushort_t* __restrict__ q_ws, ushort_t* __restrict__ k_ws,
    ushort_t* __restrict__ vt_ws) {
  const int rt = blockIdx.x;
  const int iw = blockIdx.y >> 2;
  const int ct = blockIdx.y & 3;
  const float* W = (iw == 0) ? Wq : (iw == 1) ? Wk : Wv;
  const float* bs = (iw == 0) ? bq : (iw == 1) ? bk : bv;
  const int tid = threadIdx.x;

  __shared__ float fsm[32 * 64];
  __shared__ ushort_t re[32 * 256];

  {
    const float4* fg = reinterpret_cast<const float4*>(feat + (size_t)rt * 32 * 64);
    float4* fs = reinterpret_cast<float4*>(fsm);
    fs[tid] = fg[tid];
    fs[tid + 256] = fg[tid + 256];
  }
  __syncthreads();

  const int j = ct * 256 + tid;
  float acc[32];
  {
    const float b0 = bs[j];
#pragma unroll
    for (int r = 0; r < 32; ++r) acc[r] = b0;
  }
  for (int f4 = 0; f4 < 16; ++f4) {
    const float w0 = W[(f4 * 4 + 0) * 1024 + j];
    const float w1 = W[(f4 * 4 + 1) * 1024 + j];
    const float w2 = W[(f4 * 4 + 2) * 1024 + j];
    const float w3 = W[(f4 * 4 + 3) * 1024 + j];
#pragma unroll
    for (int r = 0; r < 32; ++r) {
      const float4 fv = *reinterpret_cast<const float4*>(&fsm[r * 64 + f4 * 4]);
      acc[r] = fmaf(fv.x, w0, acc[r]);
      acc[r] = fmaf(fv.y, w1, acc[r]);
      acc[r] = fmaf(fv.z, w2, acc[r]);
      acc[r] = fmaf(fv.w, w3, acc[r]);
    }
  }
  if (iw == 0) {
#pragma unroll
    for (int r = 0; r < 32; ++r) acc[r] *= QSCALE;  // fold 1/T*log2e into Q
  }

  const int b = (rt * 32) >> 11;
  const int d0 = (rt * 32) & 2047;
  if (iw == 2) {
    const int h = j >> 7, cc = j & 127;
    ushort_t us[32];
#pragma unroll
    for (int r = 0; r < 32; ++r) us[r] = f2bf(acc[r]);
    ushort_t* dst = vt_ws + ((size_t)((h * BATCH + b) * CW + cc)) * DEP + d0;
#pragma unroll
    for (int i = 0; i < 4; ++i) {
      unsigned int a0 = us[8 * i + 0] | ((unsigned int)us[8 * i + 1] << 16);
      unsigned int a1 = us[8 * i + 2] | ((unsigned int)us[8 * i + 3] << 16);
      unsigned int a2 = us[8 * i + 4] | ((unsigned int)us[8 * i + 5] << 16);
      unsigned int a3 = us[8 * i + 6] | ((unsigned int)us[8 * i + 7] << 16);
      i32x4 v4 = {(int)a0, (int)a1, (int)a2, (int)a3};
      *reinterpret_cast<i32x4*>(dst + i * 8) = v4;
    }
  } else {
    ushort_t* wsb = (iw == 0) ? q_ws : k_ws;
#pragma unroll
    for (int r = 0; r < 32; ++r) re[r * 256 + tid] = f2bf(acc[r]);
    __syncthreads();
#pragma unroll
    for (int i = 0; i < 4; ++i) {
      const int id = tid + i * 256;
      const int r = id >> 5;
      const int c8 = (id & 31) * 8;
      const int jj = ct * 256 + c8;
      const int hh = jj >> 7, c2 = jj & 127;
      ushort_t* dst = wsb + ((size_t)((hh * BATCH + b) * DEP) + d0 + r) * CW + c2;
      *reinterpret_cast<i32x4*>(dst) = *reinterpret_cast<const i32x4*>(&re[r * 256 + c8]);
    }
  }
}

// ---------------------------------------------------------------------------
// Kernel 2: single-pass attention. 2048 blocks (32 hb x 64 q-tiles of 32),
// 512 threads (8 waves). Phase A: QK^T once, exp2 once, unnormalized P~ (bf16)
// -> 128KB LDS, row-sums on the fly, NO barriers in the loop. Phase B:
// normalize-on-write attn + PV with inv folded into the epilogue.
// ---------------------------------------------------------------------------
__global__ __launch_bounds__(512, 2) void attn_kernel(
    const ushort_t* __restrict__ q_ws, const ushort_t* __restrict__ k_ws,
    const ushort_t* __restrict__ vt_ws, float* __restrict__ out,
    float* __restrict__ attn) {
  extern __shared__ char smem[];                    // [32 q][2048 key] bf16, swizzled
  float* rsbuf = (float*)(smem + 131072);           // [4 kw][32 q]
  float* invbuf = rsbuf + 128;                      // [32 q]

  // XCD-aware swizzle: cluster each hb's blocks on one XCD (2048 % 8 == 0)
  const int bid0 = blockIdx.x;
  const int wg = (bid0 & 7) * 256 + (bid0 >> 3);
  const int hb = wg >> 6;
  const int qbase = (wg & 63) * 32;

  const int tid = threadIdx.x;
  const int w = tid >> 6, l = tid & 63;
  const int lg = l >> 4, ll = l & 15;

  // ---- phase A: wave (kw, qh) covers 16 keys x 16 q per 64-key tile ----
  const int kw = w & 3, qh = w >> 2;
  bf16x8 qf[4];
  {
    const ushort_t* qrow =
        q_ws + ((size_t)(hb * DEP + qbase + 16 * qh + ll)) * CW + lg * 8;
#pragma unroll
    for (int ks = 0; ks < 4; ++ks)
      qf[ks] = *reinterpret_cast<const bf16x8*>(qrow + ks * 32);
  }
  const int qloc = 16 * qh + ll;
  const int pswz = (qloc & 7) << 4;
  float rs = 0.f;
  const ushort_t* kb0 = k_ws + (size_t)hb * DEP * CW + (size_t)(16 * kw + ll) * CW + lg * 8;
  for (int kt = 0; kt < 32; ++kt) {
    const ushort_t* krow = kb0 + (size_t)kt * 64 * CW;
    bf16x8 ka[4];
#pragma unroll
    for (int ks = 0; ks < 4; ++ks)
      ka[ks] = *reinterpret_cast<const bf16x8*>(krow + ks * 32);
    f32x4 acc = {0.f, 0.f, 0.f, 0.f};
#pragma unroll
    for (int ks = 0; ks < 4; ++ks) acc = MFMA16(ka[ks], qf[ks], acc);
    float pv0 = EXP2(acc[0]), pv1 = EXP2(acc[1]);
    float pv2 = EXP2(acc[2]), pv3 = EXP2(acc[3]);
    rs += (pv0 + pv1) + (pv2 + pv3);
    unsigned int lo = f2bf(pv0) | ((unsigned int)f2bf(pv1) << 16);
    unsigned int hi = f2bf(pv2) | ((unsigned int)f2bf(pv3) << 16);
    const int key = kt * 64 + 16 * kw + 4 * lg;
    const int boff = (qloc * 4096 + key * 2) ^ pswz;
    *reinterpret_cast<i32x2*>(smem + boff) = i32x2{(int)lo, (int)hi};
  }
  rs += __shfl_xor(rs, 16);
  rs += __shfl_xor(rs, 32);
  if (lg == 0) rsbuf[kw * 32 + qloc] = rs;
  __syncthreads();
  if (tid < 32)
    invbuf[tid] = 1.f / ((rsbuf[tid] + rsbuf[32 + tid]) + (rsbuf[64 + tid] + rsbuf[96 + tid]));
  __syncthreads();

  // ---- phase B: wave (cp, qhb) owns 32 c x 16 q; attn normalize-on-write ----
  const int cp = w >> 1, qhb = w & 1;
  const int qloc2 = 16 * qhb + ll;
  const int pswz2 = (qloc2 & 7) << 4;
  const int qA = tid >> 4;
  const float invA = invbuf[qA];
  float* attnrow = attn + (size_t)hb * DEP * DEP + (size_t)(qbase + qA) * DEP;
  const ushort_t* vb0 = vt_ws + (size_t)hb * CW * DEP;

  f32x4 accO[2] = {{0.f, 0.f, 0.f, 0.f}, {0.f, 0.f, 0.f, 0.f}};
  for (int kt = 0; kt < 32; ++kt) {
#pragma unroll
    for (int ks2 = 0; ks2 < 2; ++ks2) {
      const int kb = kt * 64 + ks2 * 32 + lg * 8;
      const int boff = (qloc2 * 4096 + kb * 2) ^ pswz2;
      bf16x8 pb = *reinterpret_cast<const bf16x8*>(smem + boff);
#pragma unroll
      for (int i = 0; i < 2; ++i) {
        const int c = 16 * (2 * cp + i) + ll;
        bf16x8 va = *reinterpret_cast<const bf16x8*>(vb0 + (size_t)c * DEP + kb);
        accO[i] = MFMA16(va, pb, accO[i]);
      }
    }
    if ((kt & 1) == 0) {  // attn write: 128-key window, interleaved with MFMA
      const int key8 = kt * 64 + (tid & 15) * 8;
      const int boff = (qA * 4096 + key8 * 2) ^ ((qA & 7) << 4);
      bf16x8 pr = *reinterpret_cast<const bf16x8*>(smem + boff);
      f32x4 s0, s1;
#pragma unroll
      for (int r = 0; r < 4; ++r) {
        s0[r] = bf2f((ushort_t)pr[r]) * invA;
        s1[r] = bf2f((ushort_t)pr[r + 4]) * invA;
      }
      *reinterpret_cast<f32x4*>(attnrow + key8) = s0;
      *reinterpret_cast<f32x4*>(attnrow + key8 + 4) = s1;
    }
  }

  // epilogue: out^T frags, normalization folded in
  const int hh = hb >> 2, b = hb & 3;
  const float invO = invbuf[qloc2];
#pragma unroll
  for (int i = 0; i < 2; ++i) {
    const int c0 = 16 * (2 * cp + i) + 4 * lg;
    f32x4 r;
#pragma unroll
    for (int r4 = 0; r4 < 4; ++r4) r[r4] = accO[i][r4] * invO;
    float* dst = out + ((size_t)(b * 16 + hh * 2 + (c0 >> 6)) * DEP + qbase + qloc2) * 64 + (c0 & 63);
    *reinterpret_cast<f32x4*>(dst) = r;
  }
}

extern "C" void kernel_launch(void* const* d_in, const int* in_sizes, int n_in,
                              void* d_out, int out_size, void* d_ws, size_t ws_size,
                              hipStream_t stream) {
  const float* feat = (const float*)d_in[0];
  const float* Wq = (const float*)d_in[1];
  const float* bq = (const float*)d_in[2];
  const float* Wk = (const float*)d_in[3];
  const float* bk = (const float*)d_in[4];
  const float* Wv = (const float*)d_in[5];
  const float* bv = (const float*)d_in[6];

  ushort_t* q_ws = (ushort_t*)d_ws;
  ushort_t* k_ws = q_ws + (size_t)HBn * DEP * CW;
  ushort_t* vt_ws = k_ws + (size_t)HBn * DEP * CW;

  float* out = (float*)d_out;
  float* attn = out + (size_t)BATCH * 16 * DEP * 64;

  static int smem_attr_set = 0;
  if (!smem_attr_set) {
    (void)hipFuncSetAttribute((const void*)attn_kernel,
                              hipFuncAttributeMaxDynamicSharedMemorySize, 131712);
    smem_attr_set = 1;
  }

  hipLaunchKernelGGL(proj_kernel, dim3(256, 12), dim3(256), 0, stream,
                     feat, Wq, bq, Wk, bk, Wv, bv, q_ws, k_ws, vt_ws);
  hipLaunchKernelGGL(attn_kernel, dim3(2048), dim3(512), 131712, stream,
                     q_ws, k_ws, vt_ws, out, attn);
}

// Round 3
// 561.232 us; speedup vs baseline: 1.0918x; 1.0918x over previous
//
#include <hip/hip_runtime.h>
#include <hip/hip_bf16.h>

typedef unsigned short ushort_t;
typedef __attribute__((ext_vector_type(8))) short bf16x8;
typedef __attribute__((ext_vector_type(4))) float f32x4;
typedef __attribute__((ext_vector_type(16))) float f32x16;
typedef __attribute__((ext_vector_type(4))) int i32x4;

#define MFMA32(A, B, C) __builtin_amdgcn_mfma_f32_32x32x16_bf16(A, B, C, 0, 0, 0)

#if defined(__has_builtin)
#if __has_builtin(__builtin_amdgcn_exp2f)
#define EXP2(x) __builtin_amdgcn_exp2f(x)
#else
#define EXP2(x) exp2f(x)
#endif
#else
#define EXP2(x) exp2f(x)
#endif

static constexpr int BATCH = 4;
static constexpr int DEP = 2048;
static constexpr int NH = 8;
static constexpr int CW = 128;   // per-head q/k/v width
static constexpr int HBn = 32;   // NH*BATCH
// log2(e)/sqrt(2048): folded into Q at projection so logits feed exp2 directly
static constexpr float QSCALE = (float)(1.4426950408889634 / 45.254833995939045);

static __device__ __forceinline__ ushort_t f2bf(float f) {
  __hip_bfloat16 h = __float2bfloat16(f);
  return __builtin_bit_cast(ushort_t, h);
}
static __device__ __forceinline__ float bf2f(unsigned int u) {
  unsigned int v = (u & 0xffffu) << 16;
  return __builtin_bit_cast(float, v);
}
static __device__ __forceinline__ void nt_store4(float* p, f32x4 v) {
  __builtin_nontemporal_store(v, reinterpret_cast<f32x4*>(p));
}

// ---------------------------------------------------------------------------
// Kernel 1: pointwise QKV projection (Q pre-scaled by QSCALE). Unchanged (R1/R2).
//   q_ws/k_ws: bf16 [32 hb][2048 d][128 c];  vt_ws: bf16 [32 hb][128 c][2048 d]
// ---------------------------------------------------------------------------
__global__ __launch_bounds__(256) void proj_kernel(
    const float* __restrict__ feat,
    const float* __restrict__ Wq, const float* __restrict__ bq,
    const float* __restrict__ Wk, const float* __restrict__ bk,
    const float* __restrict__ Wv, const float* __restrict__ bv,
    ushort_t* __restrict__ q_ws, ushort_t* __restrict__ k_ws,
    ushort_t* __restrict__ vt_ws) {
  const int rt = blockIdx.x;
  const int iw = blockIdx.y >> 2;
  const int ct = blockIdx.y & 3;
  const float* W = (iw == 0) ? Wq : (iw == 1) ? Wk : Wv;
  const float* bs = (iw == 0) ? bq : (iw == 1) ? bk : bv;
  const int tid = threadIdx.x;

  __shared__ float fsm[32 * 64];
  __shared__ ushort_t re[32 * 256];

  {
    const float4* fg = reinterpret_cast<const float4*>(feat + (size_t)rt * 32 * 64);
    float4* fs = reinterpret_cast<float4*>(fsm);
    fs[tid] = fg[tid];
    fs[tid + 256] = fg[tid + 256];
  }
  __syncthreads();

  const int j = ct * 256 + tid;
  float acc[32];
  {
    const float b0 = bs[j];
#pragma unroll
    for (int r = 0; r < 32; ++r) acc[r] = b0;
  }
  for (int f4 = 0; f4 < 16; ++f4) {
    const float w0 = W[(f4 * 4 + 0) * 1024 + j];
    const float w1 = W[(f4 * 4 + 1) * 1024 + j];
    const float w2 = W[(f4 * 4 + 2) * 1024 + j];
    const float w3 = W[(f4 * 4 + 3) * 1024 + j];
#pragma unroll
    for (int r = 0; r < 32; ++r) {
      const float4 fv = *reinterpret_cast<const float4*>(&fsm[r * 64 + f4 * 4]);
      acc[r] = fmaf(fv.x, w0, acc[r]);
      acc[r] = fmaf(fv.y, w1, acc[r]);
      acc[r] = fmaf(fv.z, w2, acc[r]);
      acc[r] = fmaf(fv.w, w3, acc[r]);
    }
  }
  if (iw == 0) {
#pragma unroll
    for (int r = 0; r < 32; ++r) acc[r] *= QSCALE;
  }

  const int b = (rt * 32) >> 11;
  const int d0 = (rt * 32) & 2047;
  if (iw == 2) {
    const int h = j >> 7, cc = j & 127;
    ushort_t us[32];
#pragma unroll
    for (int r = 0; r < 32; ++r) us[r] = f2bf(acc[r]);
    ushort_t* dst = vt_ws + ((size_t)((h * BATCH + b) * CW + cc)) * DEP + d0;
#pragma unroll
    for (int i = 0; i < 4; ++i) {
      unsigned int a0 = us[8 * i + 0] | ((unsigned int)us[8 * i + 1] << 16);
      unsigned int a1 = us[8 * i + 2] | ((unsigned int)us[8 * i + 3] << 16);
      unsigned int a2 = us[8 * i + 4] | ((unsigned int)us[8 * i + 5] << 16);
      unsigned int a3 = us[8 * i + 6] | ((unsigned int)us[8 * i + 7] << 16);
      i32x4 v4 = {(int)a0, (int)a1, (int)a2, (int)a3};
      *reinterpret_cast<i32x4*>(dst + i * 8) = v4;
    }
  } else {
    ushort_t* wsb = (iw == 0) ? q_ws : k_ws;
#pragma unroll
    for (int r = 0; r < 32; ++r) re[r * 256 + tid] = f2bf(acc[r]);
    __syncthreads();
#pragma unroll
    for (int i = 0; i < 4; ++i) {
      const int id = tid + i * 256;
      const int r = id >> 5;
      const int c8 = (id & 31) * 8;
      const int jj = ct * 256 + c8;
      const int hh = jj >> 7, c2 = jj & 127;
      ushort_t* dst = wsb + ((size_t)((hh * BATCH + b) * DEP) + d0 + r) * CW + c2;
      *reinterpret_cast<i32x4*>(dst) = *reinterpret_cast<const i32x4*>(&re[r * 256 + c8]);
    }
  }
}

// ---------------------------------------------------------------------------
// Kernel 2: single-pass attention, P~ in registers (32x32 MFMA, swapped QK^T).
// 2048 blocks (32 hb x 64 q-tiles of 32 rows), 512 threads (8 waves).
// Wave w owns 32-key tiles {w, w+8, ..., w+56}: QK^T -> exp2 -> bf16-pack ->
// shfl_xor(32) redistribution -> PV accumulate. No LDS, no barriers in loop.
// Epilogue: rowsum reduce, attn nt-stores from regs, cross-wave out reduce.
// ---------------------------------------------------------------------------
__global__ __launch_bounds__(512, 2) void attn_kernel(
    const ushort_t* __restrict__ q_ws, const ushort_t* __restrict__ k_ws,
    const ushort_t* __restrict__ vt_ws, float* __restrict__ out,
    float* __restrict__ attn) {
  extern __shared__ char smem[];                   // [8 waves][128 c][33 f32]
  float* rsbuf = (float*)(smem + 8 * 16896);       // [8][32]
  float* invbuf = rsbuf + 256;                     // [32]

  // XCD swizzle: each XCD runs 4 hb's worth of blocks back-to-back (L2 locality)
  const int bid0 = blockIdx.x;
  const int wg = (bid0 & 7) * 256 + (bid0 >> 3);
  const int hb = wg >> 6;
  const int qbase = (wg & 63) * 32;

  const int tid = threadIdx.x;
  const int w = tid >> 6, l = tid & 63;
  const int q = l & 31;   // lane's q column (32x32 col index)
  const int h = l >> 5;   // lane half

  // Q B-fragments: lane holds Q[f = fs*16 + h*8 + j][q], 8 slices of 16 feat
  bf16x8 qf[8];
  {
    const ushort_t* qrow = q_ws + ((size_t)(hb * DEP + qbase + q)) * CW + h * 8;
#pragma unroll
    for (int fs = 0; fs < 8; ++fs)
      qf[fs] = *reinterpret_cast<const bf16x8*>(qrow + fs * 16);
  }

  const ushort_t* kbase = k_ws + (size_t)hb * DEP * CW + (size_t)q * CW + h * 8;
  const ushort_t* vbase = vt_ws + (size_t)hb * CW * DEP + (size_t)q * DEP + h * 8;

  f32x16 accO[4] = {};
  i32x4 pst[8][2];      // packed unnormalized P~ bf16, PV B-frag layout
  float rs = 0.f;

#pragma unroll
  for (int j = 0; j < 8; ++j) {
    const int kt = w + 8 * j;
    // K A-fragments: lane holds K[key = kt*32+q][f = fs*16 + h*8 + j]
    const ushort_t* krow = kbase + (size_t)(kt * 32) * CW;
    bf16x8 ka[8];
#pragma unroll
    for (int fs = 0; fs < 8; ++fs)
      ka[fs] = *reinterpret_cast<const bf16x8*>(krow + fs * 16);
    f32x16 s = {};
#pragma unroll
    for (int fs = 0; fs < 8; ++fs) s = MFMA32(ka[fs], qf[fs], s);
    // p[r] = P~[key = (r&3)+8*(r>>2)+4h][q]
    float p[16];
#pragma unroll
    for (int r = 0; r < 16; ++r) {
      p[r] = EXP2(s[r]);
      rs += p[r];
    }
    unsigned int wr[8], x[8];
#pragma unroll
    for (int i = 0; i < 8; ++i)
      wr[i] = (unsigned int)f2bf(p[2 * i]) | ((unsigned int)f2bf(p[2 * i + 1]) << 16);
#pragma unroll
    for (int i = 0; i < 8; ++i) x[i] = (unsigned int)__shfl_xor((int)wr[i], 32);
    // redistribute to PV B-frag: lane holds P~[key = s*16 + h*8 + 0..7][q]
    i32x4 pb0 = {(int)(h ? x[2] : wr[0]), (int)(h ? x[3] : wr[1]),
                 (int)(h ? wr[2] : x[0]), (int)(h ? wr[3] : x[1])};
    i32x4 pb1 = {(int)(h ? x[6] : wr[4]), (int)(h ? x[7] : wr[5]),
                 (int)(h ? wr[6] : x[4]), (int)(h ? wr[7] : x[5])};
    pst[j][0] = pb0;
    pst[j][1] = pb1;
    // PV: out^T[c][q] += V^T[c][key] * P~[key][q]
#pragma unroll
    for (int ct = 0; ct < 4; ++ct) {
      const ushort_t* vrow = vbase + (size_t)(ct * 32) * DEP + kt * 32;
      bf16x8 va0 = *reinterpret_cast<const bf16x8*>(vrow);
      accO[ct] = MFMA32(va0, __builtin_bit_cast(bf16x8, pb0), accO[ct]);
      bf16x8 va1 = *reinterpret_cast<const bf16x8*>(vrow + 16);
      accO[ct] = MFMA32(va1, __builtin_bit_cast(bf16x8, pb1), accO[ct]);
    }
  }

  // ---- row sums across halves + waves ----
  rs += __shfl_xor(rs, 32);
  if (h == 0) rsbuf[w * 32 + q] = rs;
  __syncthreads();
  if (tid < 32) {
    float t = 0.f;
#pragma unroll
    for (int ww = 0; ww < 8; ++ww) t += rsbuf[ww * 32 + tid];
    invbuf[tid] = 1.f / t;
  }
  __syncthreads();

  // ---- dump accO to LDS for cross-wave reduce (padded stride 33) ----
#pragma unroll
  for (int ct = 0; ct < 4; ++ct)
#pragma unroll
    for (int r = 0; r < 16; ++r) {
      const int c = ct * 32 + (r & 3) + 8 * (r >> 2) + 4 * h;
      *reinterpret_cast<float*>(smem + (size_t)w * 16896 + c * 132 + q * 4) =
          accO[ct][r];
    }

  // ---- attn writes from registers (normalized), nontemporal ----
  {
    const float invq = invbuf[q];
    float* arow = attn + (size_t)hb * DEP * DEP + (size_t)(qbase + q) * DEP + h * 8;
#pragma unroll
    for (int j = 0; j < 8; ++j) {
      const int kt = w + 8 * j;
#pragma unroll
      for (int s2 = 0; s2 < 2; ++s2) {
        const i32x4 pw = pst[j][s2];
        f32x4 o0, o1;
#pragma unroll
        for (int i = 0; i < 4; ++i) {
          const unsigned int u = (unsigned int)pw[i];
          const float v0 = bf2f(u) * invq;
          const float v1 = bf2f(u >> 16) * invq;
          if (i < 2) { o0[2 * i] = v0; o0[2 * i + 1] = v1; }
          else       { o1[2 * (i - 2)] = v0; o1[2 * (i - 2) + 1] = v1; }
        }
        float* dst = arow + kt * 32 + s2 * 16;
        nt_store4(dst, o0);
        nt_store4(dst + 4, o1);
      }
    }
  }

  __syncthreads();

  // ---- cross-wave out reduce + store: thread t owns (q = t&31, c = (t>>5)*8..+7)
  {
    const int qr = tid & 31, cb = (tid >> 5) * 8;
    float sred[8] = {0.f, 0.f, 0.f, 0.f, 0.f, 0.f, 0.f, 0.f};
#pragma unroll
    for (int ww = 0; ww < 8; ++ww)
#pragma unroll
      for (int jj = 0; jj < 8; ++jj)
        sred[jj] += *reinterpret_cast<const float*>(
            smem + (size_t)ww * 16896 + (cb + jj) * 132 + qr * 4);
    const float iv = invbuf[qr];
    f32x4 r0, r1;
#pragma unroll
    for (int jj = 0; jj < 4; ++jj) {
      r0[jj] = sred[jj] * iv;
      r1[jj] = sred[jj + 4] * iv;
    }
    const int hh = hb >> 2, b = hb & 3;
    float* dst = out + ((size_t)(b * 16 + hh * 2 + (cb >> 6)) * DEP + qbase + qr) * 64 +
                 (cb & 63);
    nt_store4(dst, r0);
    nt_store4(dst + 4, r1);
  }
}

extern "C" void kernel_launch(void* const* d_in, const int* in_sizes, int n_in,
                              void* d_out, int out_size, void* d_ws, size_t ws_size,
                              hipStream_t stream) {
  const float* feat = (const float*)d_in[0];
  const float* Wq = (const float*)d_in[1];
  const float* bq = (const float*)d_in[2];
  const float* Wk = (const float*)d_in[3];
  const float* bk = (const float*)d_in[4];
  const float* Wv = (const float*)d_in[5];
  const float* bv = (const float*)d_in[6];

  ushort_t* q_ws = (ushort_t*)d_ws;
  ushort_t* k_ws = q_ws + (size_t)HBn * DEP * CW;
  ushort_t* vt_ws = k_ws + (size_t)HBn * DEP * CW;

  float* out = (float*)d_out;
  float* attn = out + (size_t)BATCH * 16 * DEP * 64;

  constexpr int ATTN_LDS = 8 * 16896 + 256 * 4 + 32 * 4;  // 136448 B
  static int smem_attr_set = 0;
  if (!smem_attr_set) {
    (void)hipFuncSetAttribute((const void*)attn_kernel,
                              hipFuncAttributeMaxDynamicSharedMemorySize, ATTN_LDS);
    smem_attr_set = 1;
  }

  hipLaunchKernelGGL(proj_kernel, dim3(256, 12), dim3(256), 0, stream,
                     feat, Wq, bq, Wk, bk, Wv, bv, q_ws, k_ws, vt_ws);
  hipLaunchKernelGGL(attn_kernel, dim3(2048), dim3(512), ATTN_LDS, stream,
                     q_ws, k_ws, vt_ws, out, attn);
}

// Round 4
// 445.235 us; speedup vs baseline: 1.3762x; 1.2605x over previous
//
#include <hip/hip_runtime.h>
#include <hip/hip_bf16.h>

typedef unsigned short ushort_t;
typedef __attribute__((ext_vector_type(8))) short bf16x8;
typedef __attribute__((ext_vector_type(4))) float f32x4;
typedef __attribute__((ext_vector_type(16))) float f32x16;
typedef __attribute__((ext_vector_type(4))) int i32x4;
typedef __attribute__((ext_vector_type(2))) int i32x2;

#define MFMA32(A, B, C) __builtin_amdgcn_mfma_f32_32x32x16_bf16(A, B, C, 0, 0, 0)

#if defined(__has_builtin)
#if __has_builtin(__builtin_amdgcn_exp2f)
#define EXP2(x) __builtin_amdgcn_exp2f(x)
#else
#define EXP2(x) exp2f(x)
#endif
#else
#define EXP2(x) exp2f(x)
#endif

static constexpr int BATCH = 4;
static constexpr int DEP = 2048;
static constexpr int NH = 8;
static constexpr int CW = 128;   // per-head q/k/v width
static constexpr int HBn = 32;   // NH*BATCH
// log2(e)/sqrt(2048): folded into Q at projection so logits feed exp2 directly
static constexpr float QSCALE = (float)(1.4426950408889634 / 45.254833995939045);

static __device__ __forceinline__ ushort_t f2bf(float f) {
  __hip_bfloat16 h = __float2bfloat16(f);
  return __builtin_bit_cast(ushort_t, h);
}
static __device__ __forceinline__ float bf2f(unsigned int u) {
  unsigned int v = (u & 0xffffu) << 16;
  return __builtin_bit_cast(float, v);
}
static __device__ __forceinline__ void nt_store4(float* p, f32x4 v) {
  __builtin_nontemporal_store(v, reinterpret_cast<f32x4*>(p));
}

// ---------------------------------------------------------------------------
// Kernel 1: pointwise QKV projection (Q pre-scaled by QSCALE). Unchanged.
//   q_ws/k_ws: bf16 [32 hb][2048 d][128 c];  vt_ws: bf16 [32 hb][128 c][2048 d]
// ---------------------------------------------------------------------------
__global__ __launch_bounds__(256) void proj_kernel(
    const float* __restrict__ feat,
    const float* __restrict__ Wq, const float* __restrict__ bq,
    const float* __restrict__ Wk, const float* __restrict__ bk,
    const float* __restrict__ Wv, const float* __restrict__ bv,
    ushort_t* __restrict__ q_ws, ushort_t* __restrict__ k_ws,
    ushort_t* __restrict__ vt_ws) {
  const int rt = blockIdx.x;
  const int iw = blockIdx.y >> 2;
  const int ct = blockIdx.y & 3;
  const float* W = (iw == 0) ? Wq : (iw == 1) ? Wk : Wv;
  const float* bs = (iw == 0) ? bq : (iw == 1) ? bk : bv;
  const int tid = threadIdx.x;

  __shared__ float fsm[32 * 64];
  __shared__ ushort_t re[32 * 256];

  {
    const float4* fg = reinterpret_cast<const float4*>(feat + (size_t)rt * 32 * 64);
    float4* fs = reinterpret_cast<float4*>(fsm);
    fs[tid] = fg[tid];
    fs[tid + 256] = fg[tid + 256];
  }
  __syncthreads();

  const int j = ct * 256 + tid;
  float acc[32];
  {
    const float b0 = bs[j];
#pragma unroll
    for (int r = 0; r < 32; ++r) acc[r] = b0;
  }
  for (int f4 = 0; f4 < 16; ++f4) {
    const float w0 = W[(f4 * 4 + 0) * 1024 + j];
    const float w1 = W[(f4 * 4 + 1) * 1024 + j];
    const float w2 = W[(f4 * 4 + 2) * 1024 + j];
    const float w3 = W[(f4 * 4 + 3) * 1024 + j];
#pragma unroll
    for (int r = 0; r < 32; ++r) {
      const float4 fv = *reinterpret_cast<const float4*>(&fsm[r * 64 + f4 * 4]);
      acc[r] = fmaf(fv.x, w0, acc[r]);
      acc[r] = fmaf(fv.y, w1, acc[r]);
      acc[r] = fmaf(fv.z, w2, acc[r]);
      acc[r] = fmaf(fv.w, w3, acc[r]);
    }
  }
  if (iw == 0) {
#pragma unroll
    for (int r = 0; r < 32; ++r) acc[r] *= QSCALE;
  }

  const int b = (rt * 32) >> 11;
  const int d0 = (rt * 32) & 2047;
  if (iw == 2) {
    const int h = j >> 7, cc = j & 127;
    ushort_t us[32];
#pragma unroll
    for (int r = 0; r < 32; ++r) us[r] = f2bf(acc[r]);
    ushort_t* dst = vt_ws + ((size_t)((h * BATCH + b) * CW + cc)) * DEP + d0;
#pragma unroll
    for (int i = 0; i < 4; ++i) {
      unsigned int a0 = us[8 * i + 0] | ((unsigned int)us[8 * i + 1] << 16);
      unsigned int a1 = us[8 * i + 2] | ((unsigned int)us[8 * i + 3] << 16);
      unsigned int a2 = us[8 * i + 4] | ((unsigned int)us[8 * i + 5] << 16);
      unsigned int a3 = us[8 * i + 6] | ((unsigned int)us[8 * i + 7] << 16);
      i32x4 v4 = {(int)a0, (int)a1, (int)a2, (int)a3};
      *reinterpret_cast<i32x4*>(dst + i * 8) = v4;
    }
  } else {
    ushort_t* wsb = (iw == 0) ? q_ws : k_ws;
#pragma unroll
    for (int r = 0; r < 32; ++r) re[r * 256 + tid] = f2bf(acc[r]);
    __syncthreads();
#pragma unroll
    for (int i = 0; i < 4; ++i) {
      const int id = tid + i * 256;
      const int r = id >> 5;
      const int c8 = (id & 31) * 8;
      const int jj = ct * 256 + c8;
      const int hh = jj >> 7, c2 = jj & 127;
      ushort_t* dst = wsb + ((size_t)((hh * BATCH + b) * DEP) + d0 + r) * CW + c2;
      *reinterpret_cast<i32x4*>(dst) = *reinterpret_cast<const i32x4*>(&re[r * 256 + c8]);
    }
  }
}

// ---------------------------------------------------------------------------
// Kernel 2: two-pass attention, split-c PV. 2048 blocks (32 hb x 64 q-tiles),
// 256 threads (4 waves). Wave w owns keys [w*512, w*512+512).
// Pass 1: QK^T + exp2 -> rowsums only (no stores, no barriers).
// Pass 2 per 32-key step: QK^T again, normalized P -> bf16 staged in LDS
// (2KB/wave, double-buffered), coalesced nt attn writes (128B/row runs),
// PV with wave-owned 32-channel c-slice reading ALL waves' staged P.
// accO = one f32x16 (16 regs). One barrier per step.
// ---------------------------------------------------------------------------
__global__ __launch_bounds__(256, 3) void attn_kernel(
    const ushort_t* __restrict__ q_ws, const ushort_t* __restrict__ k_ws,
    const ushort_t* __restrict__ vt_ws, float* __restrict__ out,
    float* __restrict__ attn) {
  __shared__ ushort_t stag[2][4][32 * 32];  // [buf][wave][q*32+key] bf16, swizzled
  __shared__ float rsbuf[4][32];
  __shared__ float invbuf[32];

  // XCD swizzle: per XCD, blocks of one hb run back-to-back (L2 locality)
  const int bid0 = blockIdx.x;
  const int wg = (bid0 & 7) * 256 + (bid0 >> 3);
  const int hb = wg >> 6;
  const int qbase = (wg & 63) * 32;

  const int tid = threadIdx.x;
  const int w = tid >> 6, l = tid & 63;
  const int q = l & 31, h = l >> 5;
  const int swz = (q & 7) << 3;

  // Q B-fragments: lane holds Q[f = fs*16 + h*8 + j][qbase+q]
  bf16x8 qf[8];
  {
    const ushort_t* qrow = q_ws + ((size_t)(hb * DEP + qbase + q)) * CW + h * 8;
#pragma unroll
    for (int fs = 0; fs < 8; ++fs)
      qf[fs] = *reinterpret_cast<const bf16x8*>(qrow + fs * 16);
  }

  const ushort_t* kbase =
      k_ws + (size_t)hb * DEP * CW + (size_t)q * CW + h * 8 + (size_t)(w * 512) * CW;

  // ---- pass 1: row sums ----
  float rs = 0.f;
  for (int t = 0; t < 16; ++t) {
    const ushort_t* krow = kbase + (size_t)(t * 32) * CW;
    bf16x8 ka[8];
#pragma unroll
    for (int fs = 0; fs < 8; ++fs)
      ka[fs] = *reinterpret_cast<const bf16x8*>(krow + fs * 16);
    f32x16 s = {};
#pragma unroll
    for (int fs = 0; fs < 8; ++fs) s = MFMA32(ka[fs], qf[fs], s);
#pragma unroll
    for (int r = 0; r < 16; ++r) rs += EXP2(s[r]);
  }
  rs += __shfl_xor(rs, 32);
  if (h == 0) rsbuf[w][q] = rs;
  __syncthreads();
  if (tid < 32)
    invbuf[tid] =
        1.f / ((rsbuf[0][tid] + rsbuf[1][tid]) + (rsbuf[2][tid] + rsbuf[3][tid]));
  __syncthreads();
  const float invq = invbuf[q];

  // ---- pass 2 ----
  char* mytile[2] = {(char*)&stag[0][w][0], (char*)&stag[1][w][0]};

  auto STAGE = [&](int t, int buf) {
    const ushort_t* krow = kbase + (size_t)(t * 32) * CW;
    bf16x8 ka[8];
#pragma unroll
    for (int fs = 0; fs < 8; ++fs)
      ka[fs] = *reinterpret_cast<const bf16x8*>(krow + fs * 16);
    f32x16 s = {};
#pragma unroll
    for (int fs = 0; fs < 8; ++fs) s = MFMA32(ka[fs], qf[fs], s);
    char* tb = mytile[buf];
#pragma unroll
    for (int i = 0; i < 8; ++i) {
      const float p0 = EXP2(s[2 * i]) * invq;
      const float p1 = EXP2(s[2 * i + 1]) * invq;
      const unsigned int pk =
          (unsigned int)f2bf(p0) | ((unsigned int)f2bf(p1) << 16);
      const int key0 = ((2 * i) & 3) + 8 * ((2 * i) >> 2) + 4 * h;
      const int boff = (q * 64 + key0 * 2) ^ swz;
      *reinterpret_cast<unsigned int*>(tb + boff) = pk;
    }
  };

  f32x16 accO = {};
  float* attnbase = attn + (size_t)hb * DEP * DEP + (size_t)qbase * DEP;
  const ushort_t* vb =
      vt_ws + (size_t)hb * CW * DEP + (size_t)(w * 32 + q) * DEP + h * 8;

  STAGE(0, 0);
  __syncthreads();

  for (int t = 0; t < 16; ++t) {
    const int buf = t & 1;
    if (t < 15) STAGE(t + 1, buf ^ 1);

    // attn write: own tile t -> rows qbase+0..31, cols w*512 + t*32 .. +32
    {
      char* tb = mytile[buf];
      const int colb = w * 512 + t * 32 + (l & 7) * 4;
#pragma unroll
      for (int ii = 0; ii < 4; ++ii) {
        const int row = ii * 8 + (l >> 3);
        const int boff = (row * 64 + (l & 7) * 8) ^ ((row & 7) << 3);
        const i32x2 pr = *reinterpret_cast<const i32x2*>(tb + boff);
        f32x4 v;
        v[0] = bf2f((unsigned int)pr[0]);
        v[1] = bf2f(((unsigned int)pr[0]) >> 16);
        v[2] = bf2f((unsigned int)pr[1]);
        v[3] = bf2f(((unsigned int)pr[1]) >> 16);
        nt_store4(attnbase + (size_t)row * DEP + colb, v);
      }
    }

    // PV: accO[c = w*32 + m][q] += sum over all 4 waves' staged tiles
#pragma unroll
    for (int w2 = 0; w2 < 4; ++w2) {
      const char* tb = (const char*)&stag[buf][w2][0];
      const ushort_t* vchunk = vb + w2 * 512 + t * 32;
#pragma unroll
      for (int kh = 0; kh < 2; ++kh) {
        const int base = q * 64 + 32 * kh + 16 * h;
        const i32x2 b0 = *reinterpret_cast<const i32x2*>(tb + ((base + 0) ^ swz));
        const i32x2 b1 = *reinterpret_cast<const i32x2*>(tb + ((base + 8) ^ swz));
        i32x4 pbi = {b0[0], b0[1], b1[0], b1[1]};
        bf16x8 va = *reinterpret_cast<const bf16x8*>(vchunk + kh * 16);
        accO = MFMA32(va, __builtin_bit_cast(bf16x8, pbi), accO);
      }
    }
    __syncthreads();
  }

  // ---- out store: lane owns col q, c-slice [w*32, w*32+32) ----
  {
    const int hh = hb >> 2, b = hb & 3;
#pragma unroll
    for (int r = 0; r < 16; ++r) {
      const int c = w * 32 + (r & 3) + 8 * (r >> 2) + 4 * h;
      out[((size_t)(b * 16 + hh * 2 + (c >> 6)) * DEP + qbase + q) * 64 + (c & 63)] =
          accO[r];
    }
  }
}

extern "C" void kernel_launch(void* const* d_in, const int* in_sizes, int n_in,
                              void* d_out, int out_size, void* d_ws, size_t ws_size,
                              hipStream_t stream) {
  const float* feat = (const float*)d_in[0];
  const float* Wq = (const float*)d_in[1];
  const float* bq = (const float*)d_in[2];
  const float* Wk = (const float*)d_in[3];
  const float* bk = (const float*)d_in[4];
  const float* Wv = (const float*)d_in[5];
  const float* bv = (const float*)d_in[6];

  ushort_t* q_ws = (ushort_t*)d_ws;
  ushort_t* k_ws = q_ws + (size_t)HBn * DEP * CW;
  ushort_t* vt_ws = k_ws + (size_t)HBn * DEP * CW;

  float* out = (float*)d_out;
  float* attn = out + (size_t)BATCH * 16 * DEP * 64;

  hipLaunchKernelGGL(proj_kernel, dim3(256, 12), dim3(256), 0, stream,
                     feat, Wq, bq, Wk, bk, Wv, bv, q_ws, k_ws, vt_ws);
  hipLaunchKernelGGL(attn_kernel, dim3(2048), dim3(256), 0, stream,
                     q_ws, k_ws, vt_ws, out, attn);
}